// Round 2
// baseline (491.010 us; speedup 1.0000x reference)
//
#include <hip/hip_runtime.h>
#include <hip/hip_bf16.h>
#include <math.h>

#define N 8192
#define TILE 2048
#define SCAN_BLOCK 64
#define SCAN_GRID (N / SCAN_BLOCK)   // 128 blocks -> 128 CUs

// Mirror the reference float32 pipeline exactly:
//   i = round((log(512) - log(w)) / log(1.2))          [all f32 ops, round = RNE]
//   di = (512*(1-g)/(1+g)) / 1.2^i = 128 / 1.2^i
//   qx = round(x/di - 0.5)
//   code = qx + qy*1e4 + i*1e8 + j*1e12  (int64)
__device__ __forceinline__ long long hash_code(float x, float y, float w, float h) {
    // correctly-rounded f32 transcendentals via double
    const float LOG_ALPHA = (float)log((double)1.2f);   // log of f32(1.2)
    const float LOGW0     = (float)log(512.0);          // W0 == H0 == 512
    float i_f = rintf((LOGW0 - (float)log((double)w)) / LOG_ALPHA);
    float j_f = rintf((LOGW0 - (float)log((double)h)) / LOG_ALPHA);
    float pi  = (float)pow((double)1.2f, (double)i_f);
    float pj  = (float)pow((double)1.2f, (double)j_f);
    float di  = 128.0f / pi;
    float dj  = 128.0f / pj;
    float qx  = rintf(x / di - 0.5f);
    float qy  = rintf(y / dj - 0.5f);
    return (long long)qx
         + (long long)qy * 10000LL
         + (long long)i_f * 100000000LL
         + (long long)j_f * 1000000000000LL;
}

// K1: compute codes, zero the int32 output (padded unique slots must be 0).
__global__ void k_codes(const float4* __restrict__ rects,
                        long long* __restrict__ codes,
                        int* __restrict__ out) {
    int t = blockIdx.x * blockDim.x + threadIdx.x;
    float4 r = rects[t];                     // (x, y, w, h) row-major, coalesced 16B
    codes[t] = hash_code(r.x, r.y, r.z, r.w);
    out[t] = 0;
}

// K2: winner[i] = 1 iff i is argmax-of-conf (first-index tie-break) in its bucket.
__global__ void k_winner(const long long* __restrict__ codes,
                         const float* __restrict__ conf,
                         int* __restrict__ winner) {
    __shared__ long long s_code[TILE];
    __shared__ float     s_conf[TILE];
    int i = blockIdx.x * blockDim.x + threadIdx.x;
    long long ci = codes[i];
    float     fi = conf[i];
    int lose = 0;
    for (int tb = 0; tb < N; tb += TILE) {
        for (int k = threadIdx.x; k < TILE; k += blockDim.x) {
            s_code[k] = codes[tb + k];
            s_conf[k] = conf[tb + k];
        }
        __syncthreads();
        #pragma unroll 8
        for (int k = 0; k < TILE; ++k) {
            long long cj = s_code[k];        // wave-uniform LDS broadcast
            float     fj = s_conf[k];
            int j = tb + k;
            lose |= (cj == ci) & ((fj > fi) | ((fj == fi) & (j < i)));
        }
        __syncthreads();
    }
    winner[i] = !lose;
}

// K3: rank of each winner = #{winners j : code_j < code_i}  (== # unique codes
// below mine, since exactly one winner per unique code). Scatter int index.
__global__ void k_scatter(const long long* __restrict__ codes,
                          const float* __restrict__ conf,
                          const int* __restrict__ winner,
                          int* __restrict__ out) {
    __shared__ long long s_code[TILE];
    __shared__ int       s_win[TILE];
    int i = blockIdx.x * blockDim.x + threadIdx.x;
    long long ci = codes[i];
    int rank = 0;
    for (int tb = 0; tb < N; tb += TILE) {
        for (int k = threadIdx.x; k < TILE; k += blockDim.x) {
            s_code[k] = codes[tb + k];
            s_win[k]  = winner[tb + k];
        }
        __syncthreads();
        #pragma unroll 8
        for (int k = 0; k < TILE; ++k) {
            rank += s_win[k] & (s_code[k] < ci);
        }
        __syncthreads();
    }
    if (winner[i]) {
        // conf==0 edge: whole score column is 0 -> reference argmax returns 0.
        out[rank] = (conf[i] == 0.0f) ? 0 : i;
    }
}

extern "C" void kernel_launch(void* const* d_in, const int* in_sizes, int n_in,
                              void* d_out, int out_size, void* d_ws, size_t ws_size,
                              hipStream_t stream) {
    const float4* rects = (const float4*)d_in[0];   // (8192, 4) f32
    const float*  conf  = (const float*)d_in[1];    // (8192,)  f32
    int* out = (int*)d_out;                         // int32 indices

    long long* codes  = (long long*)d_ws;                            // 64 KiB
    int*       winner = (int*)((char*)d_ws + N * sizeof(long long)); // 32 KiB

    k_codes  <<<N / 256, 256, 0, stream>>>(rects, codes, out);
    k_winner <<<SCAN_GRID, SCAN_BLOCK, 0, stream>>>(codes, conf, winner);
    k_scatter<<<SCAN_GRID, SCAN_BLOCK, 0, stream>>>(codes, conf, winner, out);
}

// Round 3
// 77.719 us; speedup vs baseline: 6.3177x; 6.3177x over previous
//
#include <hip/hip_runtime.h>
#include <hip/hip_bf16.h>
#include <math.h>

#define N 8192
#define S 32                 // j-slices
#define SLICE (N / S)        // 256 j's per slice == blockDim
#define IBLK 256             // i's per block

// Mirror the reference float32 pipeline exactly (verified absmax 0.0 in R2):
//   i = round((log(512) - log(w)) / log(1.2))   [f32 ops, RNE round]
//   di = 128 / 1.2^i ;  qx = round(x/di - 0.5)
//   code = qx + qy*1e4 + i*1e8 + j*1e12  (int64, nonneg, < 2^45)
__device__ __forceinline__ long long hash_code(float x, float y, float w, float h) {
    const float LOG_ALPHA = (float)log((double)1.2f);
    const float LOGW0     = (float)log(512.0);
    float i_f = rintf((LOGW0 - (float)log((double)w)) / LOG_ALPHA);
    float j_f = rintf((LOGW0 - (float)log((double)h)) / LOG_ALPHA);
    float pi  = (float)pow((double)1.2f, (double)i_f);
    float pj  = (float)pow((double)1.2f, (double)j_f);
    float qx  = rintf(x / (128.0f / pi) - 0.5f);
    float qy  = rintf(y / (128.0f / pj) - 0.5f);
    return (long long)qx
         + (long long)qy * 10000LL
         + (long long)i_f * 100000000LL
         + (long long)j_f * 1000000000000LL;
}

// K1: pair[i] = {code, key}; key = (conf_bits<<32)|(N-1-i) so
// "j beats i" == key_j > key_i  (conf >= 0 -> float bits are order-monotone;
// tie on conf -> smaller index wins -> larger N-1-j). Zero lose/rank/out.
__global__ void k_codes(const float4* __restrict__ rects,
                        const float* __restrict__ conf,
                        ulonglong2* __restrict__ pair,
                        int* __restrict__ lose,
                        int* __restrict__ rank,
                        int* __restrict__ out) {
    int t = blockIdx.x * blockDim.x + threadIdx.x;
    float4 r = rects[t];
    unsigned long long code = (unsigned long long)hash_code(r.x, r.y, r.z, r.w);
    unsigned long long key  = ((unsigned long long)__float_as_uint(conf[t]) << 32)
                            | (unsigned int)(N - 1 - t);
    pair[t] = make_ulonglong2(code, key);
    lose[t] = 0;
    rank[t] = 0;
    out[t]  = 0;
}

// K2: thread (i, slice) checks its 256 j's; lose_i |= any j beating i.
// LDS reads are wave-uniform (broadcast, conflict-free). Atomic only on loss.
__global__ void __launch_bounds__(IBLK)
k_winner(const ulonglong2* __restrict__ pair, int* __restrict__ lose) {
    __shared__ ulonglong2 s_p[SLICE];
    int t = threadIdx.x;
    int i = blockIdx.x * IBLK + t;
    s_p[t] = pair[blockIdx.y * SLICE + t];
    ulonglong2 me = pair[i];
    __syncthreads();
    int l = 0;
    #pragma unroll 8
    for (int k = 0; k < SLICE; ++k) {
        ulonglong2 p = s_p[k];
        l |= (int)((p.x == me.x) & (p.y > me.y));
    }
    if (l) atomicOr(&lose[i], 1);
}

// K3: rank_i += #{j in slice : win_j && code_j < code_i}. Winner bit packed
// into code low bit: cw = code<<1 | win; (win && code_j<code_i) == (cw&1 && cw<ci<<1).
__global__ void __launch_bounds__(IBLK)
k_rank(const ulonglong2* __restrict__ pair, const int* __restrict__ lose,
       int* __restrict__ rank) {
    __shared__ unsigned long long s_cw[SLICE];
    int t = threadIdx.x;
    int i = blockIdx.x * IBLK + t;
    int jb = blockIdx.y * SLICE + t;
    s_cw[t] = (pair[jb].x << 1) | (unsigned long long)(lose[jb] == 0);
    unsigned long long ci2 = pair[i].x << 1;
    __syncthreads();
    int r = 0;
    #pragma unroll 8
    for (int k = 0; k < SLICE; ++k) {
        unsigned long long cw = s_cw[k];
        r += (int)(cw & 1ULL) & (int)(cw < ci2);
    }
    if (r) atomicAdd(&rank[i], r);
}

// K4: winners scatter their index at their unique-rank slot.
__global__ void k_scatter(const float* __restrict__ conf,
                          const int* __restrict__ lose,
                          const int* __restrict__ rank,
                          int* __restrict__ out) {
    int i = blockIdx.x * blockDim.x + threadIdx.x;
    if (lose[i] == 0) {
        // conf==0 edge: all-zero score column -> reference argmax returns 0.
        out[rank[i]] = (conf[i] == 0.0f) ? 0 : i;
    }
}

extern "C" void kernel_launch(void* const* d_in, const int* in_sizes, int n_in,
                              void* d_out, int out_size, void* d_ws, size_t ws_size,
                              hipStream_t stream) {
    const float4* rects = (const float4*)d_in[0];   // (8192, 4) f32
    const float*  conf  = (const float*)d_in[1];    // (8192,)  f32
    int* out = (int*)d_out;                         // int32 indices

    char* ws = (char*)d_ws;
    ulonglong2* pair = (ulonglong2*)ws;                       // 128 KiB
    int* lose = (int*)(ws + N * sizeof(ulonglong2));          // 32 KiB
    int* rank = (int*)(ws + N * sizeof(ulonglong2) + N * 4);  // 32 KiB

    k_codes  <<<N / 256, 256, 0, stream>>>(rects, conf, pair, lose, rank, out);
    k_winner <<<dim3(N / IBLK, S), IBLK, 0, stream>>>(pair, lose);
    k_rank   <<<dim3(N / IBLK, S), IBLK, 0, stream>>>(pair, lose, rank);
    k_scatter<<<N / 256, 256, 0, stream>>>(conf, lose, rank, out);
}